// Round 2
// baseline (163.163 us; speedup 1.0000x reference)
//
#include <hip/hip_runtime.h>

#define BB 2
#define SS 2048
#define DD 1024
#define HH 16
#define HDIM 64
#define MTOT 4096  // B*S

typedef unsigned short u16;
typedef __bf16 bf16_t;
typedef bf16_t bf16x8 __attribute__((ext_vector_type(8)));
typedef float floatx4 __attribute__((ext_vector_type(4)));

__device__ __forceinline__ float bf2f(u16 u) {
  union { unsigned int i; float f; } x;
  x.i = ((unsigned int)u) << 16;
  return x.f;
}
// round-to-nearest-even f32 -> bf16 (finite inputs only)
__device__ __forceinline__ u16 f2bf(float f) {
  union { float f; unsigned int i; } x;
  x.f = f;
  unsigned int r = x.i + 0x7fffu + ((x.i >> 16) & 1u);
  return (u16)(r >> 16);
}

// async global->LDS, 16B per lane. LDS dest = wave-uniform base + lane*16.
__device__ __forceinline__ void gload16(const u16* g, u16* l) {
  __builtin_amdgcn_global_load_lds(
      (const __attribute__((address_space(1))) unsigned int*)g,
      (__attribute__((address_space(3))) unsigned int*)l, 16, 0, 0);
}

// ---------------- kernel 1: fp32 -> bf16 cast of hs, Wq, Wk, Wv + zero mfull ----------------
// float4-granular; segments: hs 1048576 f4, weights 3x262144 f4, mfull-zero 32768 f4.
__global__ __launch_bounds__(256) void cast_to_bf16(
    const float* __restrict__ hs, const float* __restrict__ wq,
    const float* __restrict__ wk, const float* __restrict__ wv,
    u16* __restrict__ hs_b, u16* __restrict__ wq_b,
    u16* __restrict__ wk_b, u16* __restrict__ wv_b,
    float* __restrict__ mfull) {
  int fid = blockIdx.x * 256 + threadIdx.x;  // 0 .. 1867775
  if (fid >= 1835008) {  // zero mfull (32 bh * 4096 floats = 32768 float4)
    int z = fid - 1835008;
    float4 zero = {0.f, 0.f, 0.f, 0.f};
    reinterpret_cast<float4*>(mfull)[z] = zero;
    return;
  }
  const float* src;
  u16* dst;
  int local;
  if (fid < 1048576) { src = hs; dst = hs_b; local = fid; }
  else if (fid < 1310720) { src = wq; dst = wq_b; local = fid - 1048576; }
  else if (fid < 1572864) { src = wk; dst = wk_b; local = fid - 1310720; }
  else { src = wv; dst = wv_b; local = fid - 1572864; }
  float4 v = reinterpret_cast<const float4*>(src)[local];
  ushort4 o;
  o.x = f2bf(v.x); o.y = f2bf(v.y); o.z = f2bf(v.z); o.w = f2bf(v.w);
  reinterpret_cast<ushort4*>(dst)[local] = o;
}

// ---------------- kernel 2: fused QKV projection (gemm_bt, m97 structure) ----------------
// C[m,n] = sum_k A[m,k] * W[n,k] + bias[n].  A: [4096,1024] bf16, W: [1024,1024] bf16.
// 128x128 tile, BK=32, LDS tiles UNPADDED (global_load_lds lane-contiguous constraint).
#define BKK 32
__global__ __launch_bounds__(256) void qkv_gemm_kernel(
    const u16* __restrict__ A,
    const u16* __restrict__ Wq, const u16* __restrict__ Wk, const u16* __restrict__ Wv,
    const float* __restrict__ bq, const float* __restrict__ bk, const float* __restrict__ bv,
    u16* __restrict__ Qo, u16* __restrict__ Ko, u16* __restrict__ Vo) {
  __shared__ u16 sA[128 * BKK];
  __shared__ u16 sB[128 * BKK];
  const int mt = blockIdx.y, ntall = blockIdx.x;
  const int seg = ntall >> 3, nt = ntall & 7;
  const u16* Wp = (seg == 0) ? Wq : (seg == 1) ? Wk : Wv;
  const float* bp = (seg == 0) ? bq : (seg == 1) ? bk : bv;
  u16* Out = (seg == 0) ? Qo : (seg == 1) ? Ko : Vo;
  const int m0 = mt * 128, n0 = nt * 128;
  const int tid = threadIdx.x;
  const int lane = tid & 63, wave = tid >> 6;
  const int wm = (wave >> 1) * 64, wn = (wave & 1) * 64;
  const int quad = lane >> 4, l16 = lane & 15;
  // staging coords: per wave, 2 chunks of 1024B each; lane covers 16B.
  // chunk (wave*2+c): rows (wave*2+c)*16 + (lane>>2), u16-col (lane&3)*8
  const int srow0 = wave * 32 + (lane >> 2);      // c=0 row
  const int scol = (lane & 3) * 8;
  floatx4 acc[4][4] = {};
  for (int k0 = 0; k0 < DD; k0 += BKK) {
#pragma unroll
    for (int c = 0; c < 2; ++c) {
      int r = srow0 + c * 16;
      gload16(A + (size_t)(m0 + r) * DD + k0 + scol, sA + r * BKK + scol);
      gload16(Wp + (size_t)(n0 + r) * DD + k0 + scol, sB + r * BKK + scol);
    }
    __syncthreads();  // drains vmcnt(0) -> LDS tiles complete
    bf16x8 af[4], bfr[4];
#pragma unroll
    for (int i = 0; i < 4; ++i) {
      af[i]  = *reinterpret_cast<const bf16x8*>(sA + (wm + i * 16 + l16) * BKK + quad * 8);
      bfr[i] = *reinterpret_cast<const bf16x8*>(sB + (wn + i * 16 + l16) * BKK + quad * 8);
    }
#pragma unroll
    for (int i = 0; i < 4; ++i)
#pragma unroll
      for (int j = 0; j < 4; ++j)
        acc[i][j] = __builtin_amdgcn_mfma_f32_16x16x32_bf16(af[i], bfr[j], acc[i][j], 0, 0, 0);
    __syncthreads();
  }
  // epilogue: C/D layout col=lane&15, row=quad*4+r
#pragma unroll
  for (int j = 0; j < 4; ++j) {
    int col = n0 + wn + j * 16 + l16;
    float bias = bp[col];
#pragma unroll
    for (int i = 0; i < 4; ++i) {
#pragma unroll
      for (int r = 0; r < 4; ++r) {
        int row = m0 + wm + i * 16 + quad * 4 + r;
        Out[(size_t)row * DD + col] = f2bf(acc[i][j][r] + bias);
      }
    }
  }
}

// ---------------- kernel 3: M[b,h,e,d] += sum_s mask[s]*K[s,e]*V[s,d] (atomic) ----------------
// grid (16 s-superchunks of 128, 32 bh); block 256, each thread a 4x4 (e,d) tile.
__global__ __launch_bounds__(256) void m_partial_kernel(
    const u16* __restrict__ Kb, const u16* __restrict__ Vb,
    const float* __restrict__ am, float* __restrict__ mfull) {
  __shared__ float sK[64 * 68];
  __shared__ float sV[64 * 68];
  const int bh = blockIdx.y;     // 0..31
  const int b = bh >> 4, h = bh & 15;
  const int tid = threadIdx.x;
  const int e0 = (tid & 15) * 4, d0 = (tid >> 4) * 4;
  float acc[4][4] = {};
  for (int cs = 0; cs < 2; ++cs) {
    const int s0 = (blockIdx.x * 2 + cs) * 64;
    if (cs) __syncthreads();  // protect LDS before restage
#pragma unroll
    for (int c = 0; c < 2; ++c) {
      int L = tid + c * 256;
      int srow = L >> 3;            // 0..63
      int col = (L & 7) * 8;        // 0..56
      size_t g = (size_t)(b * SS + s0 + srow) * DD + h * HDIM + col;
      uint4 kraw = *reinterpret_cast<const uint4*>(Kb + g);
      uint4 vraw = *reinterpret_cast<const uint4*>(Vb + g);
      float m = (am[b * SS + s0 + srow] >= 0.f) ? 1.f : 0.f;
      unsigned int kw[4] = {kraw.x, kraw.y, kraw.z, kraw.w};
      unsigned int vw[4] = {vraw.x, vraw.y, vraw.z, vraw.w};
#pragma unroll
      for (int q = 0; q < 4; ++q) {
        sK[srow * 68 + col + 2 * q]     = m * bf2f((u16)(kw[q] & 0xffffu));
        sK[srow * 68 + col + 2 * q + 1] = m * bf2f((u16)(kw[q] >> 16));
        sV[srow * 68 + col + 2 * q]     = bf2f((u16)(vw[q] & 0xffffu));
        sV[srow * 68 + col + 2 * q + 1] = bf2f((u16)(vw[q] >> 16));
      }
    }
    __syncthreads();
    for (int s = 0; s < 64; ++s) {
      float4 kk = *reinterpret_cast<const float4*>(&sK[s * 68 + e0]);
      float4 vv = *reinterpret_cast<const float4*>(&sV[s * 68 + d0]);
      float ka[4] = {kk.x, kk.y, kk.z, kk.w};
      float va[4] = {vv.x, vv.y, vv.z, vv.w};
#pragma unroll
      for (int i = 0; i < 4; ++i)
#pragma unroll
        for (int j = 0; j < 4; ++j) acc[i][j] += ka[i] * va[j];
    }
  }
  float* outp = mfull + (size_t)bh * 4096;
#pragma unroll
  for (int i = 0; i < 4; ++i)
#pragma unroll
    for (int j = 0; j < 4; ++j)
      atomicAdd(&outp[(e0 + i) * 64 + d0 + j], acc[i][j]);
}

// ---------------- kernel 4: ctx[m, h*64+d] = sum_e Q[m, h*64+e] * M[bh,e,d] ----------------
// grid (64 m-chunks of 64, 16 heads); block 256, thread = 4x4 (m,d) tile, e-chunks of 4.
__global__ __launch_bounds__(256) void ctx_kernel(
    const u16* __restrict__ Qb, const float* __restrict__ M, float* __restrict__ Out) {
  __shared__ float sM[64 * 68];
  __shared__ float sQ[64 * 68];
  const int mchunk = blockIdx.x;  // 0..63
  const int h = blockIdx.y;       // 0..15
  const int m0 = mchunk * 64;
  const int b = m0 >> 11;         // m0 / 2048
  const int bh = b * HH + h;
  const int tid = threadIdx.x;
  const float* Mp = M + (size_t)bh * 4096;
#pragma unroll
  for (int c = 0; c < 16; ++c) {
    int L = c * 256 + tid;
    int e = L >> 6, d = L & 63;
    sM[e * 68 + d] = Mp[L];
  }
#pragma unroll
  for (int c = 0; c < 2; ++c) {
    int L = tid + c * 256;
    int row = L >> 3, col = (L & 7) * 8;
    uint4 q = *reinterpret_cast<const uint4*>(Qb + (size_t)(m0 + row) * DD + h * HDIM + col);
    unsigned int w[4] = {q.x, q.y, q.z, q.w};
#pragma unroll
    for (int t = 0; t < 4; ++t) {
      sQ[row * 68 + col + 2 * t]     = bf2f((u16)(w[t] & 0xffffu));
      sQ[row * 68 + col + 2 * t + 1] = bf2f((u16)(w[t] >> 16));
    }
  }
  __syncthreads();
  const int d0 = (tid & 15) * 4, ml0 = (tid >> 4) * 4;
  float acc[4][4] = {};
  for (int e4 = 0; e4 < 64; e4 += 4) {
    float4 mm[4], qq[4];
#pragma unroll
    for (int t = 0; t < 4; ++t)
      mm[t] = *reinterpret_cast<const float4*>(&sM[(e4 + t) * 68 + d0]);
#pragma unroll
    for (int i = 0; i < 4; ++i)
      qq[i] = *reinterpret_cast<const float4*>(&sQ[(ml0 + i) * 68 + e4]);
    float ma[4][4], qa[4][4];
#pragma unroll
    for (int t = 0; t < 4; ++t) {
      ma[t][0] = mm[t].x; ma[t][1] = mm[t].y; ma[t][2] = mm[t].z; ma[t][3] = mm[t].w;
      qa[t][0] = qq[t].x; qa[t][1] = qq[t].y; qa[t][2] = qq[t].z; qa[t][3] = qq[t].w;
    }
#pragma unroll
    for (int i = 0; i < 4; ++i)
#pragma unroll
      for (int t = 0; t < 4; ++t)
#pragma unroll
        for (int j = 0; j < 4; ++j)
          acc[i][j] += qa[i][t] * ma[t][j];
  }
#pragma unroll
  for (int i = 0; i < 4; ++i) {
    float4 o = {acc[i][0], acc[i][1], acc[i][2], acc[i][3]};
    *reinterpret_cast<float4*>(Out + (size_t)(m0 + ml0 + i) * DD + h * HDIM + d0) = o;
  }
}

extern "C" void kernel_launch(void* const* d_in, const int* in_sizes, int n_in,
                              void* d_out, int out_size, void* d_ws, size_t ws_size,
                              hipStream_t stream) {
  const float* hs = (const float*)d_in[0];
  const float* am = (const float*)d_in[1];
  const float* wq = (const float*)d_in[2];
  const float* bq = (const float*)d_in[3];
  const float* wk = (const float*)d_in[4];
  const float* bk = (const float*)d_in[5];
  const float* wv = (const float*)d_in[6];
  const float* bv = (const float*)d_in[7];
  float* out = (float*)d_out;
  char* ws = (char*)d_ws;

  // workspace layout (bytes), all 16B-aligned; total ~40 MB
  u16* hs_b = (u16*)(ws);                  // 8 MiB  [4096,1024] bf16
  u16* wq_b = (u16*)(ws + 8388608);        // 2 MiB
  u16* wk_b = (u16*)(ws + 10485760);       // 2 MiB
  u16* wv_b = (u16*)(ws + 12582912);       // 2 MiB
  u16* q_b  = (u16*)(ws + 14680064);       // 8 MiB
  u16* k_b  = (u16*)(ws + 23068672);       // 8 MiB
  u16* v_b  = (u16*)(ws + 31457280);       // 8 MiB
  float* mfull = (float*)(ws + 39845888);  // 512 KiB [32 bh][64][64] f32 (atomic acc)

  cast_to_bf16<<<7296, 256, 0, stream>>>(hs, wq, wk, wv, hs_b, wq_b, wk_b, wv_b, mfull);
  qkv_gemm_kernel<<<dim3(24, 32), 256, 0, stream>>>(hs_b, wq_b, wk_b, wv_b,
                                                    bq, bk, bv, q_b, k_b, v_b);
  m_partial_kernel<<<dim3(16, 32), 256, 0, stream>>>(k_b, v_b, am, mfull);
  ctx_kernel<<<dim3(64, 16), 256, 0, stream>>>(q_b, mfull, out);
}

// Round 3
// 153.394 us; speedup vs baseline: 1.0637x; 1.0637x over previous
//
#include <hip/hip_runtime.h>

#define BB 2
#define SS 2048
#define DD 1024
#define HH 16
#define HDIM 64
#define MTOT 4096  // B*S

typedef unsigned short u16;
typedef __bf16 bf16_t;
typedef bf16_t bf16x8 __attribute__((ext_vector_type(8)));
typedef float floatx4 __attribute__((ext_vector_type(4)));
typedef float floatx16 __attribute__((ext_vector_type(16)));

__device__ __forceinline__ float bf2f(u16 u) {
  union { unsigned int i; float f; } x;
  x.i = ((unsigned int)u) << 16;
  return x.f;
}
// round-to-nearest-even f32 -> bf16 (finite inputs only)
__device__ __forceinline__ u16 f2bf(float f) {
  union { float f; unsigned int i; } x;
  x.f = f;
  unsigned int r = x.i + 0x7fffu + ((x.i >> 16) & 1u);
  return (u16)(r >> 16);
}

// async global->LDS, 16B per lane. LDS dest = wave-uniform base + lane*16.
__device__ __forceinline__ void gload16(const u16* g, u16* l) {
  __builtin_amdgcn_global_load_lds(
      (const __attribute__((address_space(1))) unsigned int*)g,
      (__attribute__((address_space(3))) unsigned int*)l, 16, 0, 0);
}

// ---------------- kernel 1: fp32 -> bf16 cast of hs, Wq, Wk, Wv ----------------
// float4-granular; segments: hs 1048576 f4, weights 3x262144 f4. grid*256 = 1835008 exact.
__global__ __launch_bounds__(256) void cast_to_bf16(
    const float* __restrict__ hs, const float* __restrict__ wq,
    const float* __restrict__ wk, const float* __restrict__ wv,
    u16* __restrict__ hs_b, u16* __restrict__ wq_b,
    u16* __restrict__ wk_b, u16* __restrict__ wv_b) {
  int fid = blockIdx.x * 256 + threadIdx.x;  // 0 .. 1835007
  const float* src;
  u16* dst;
  int local;
  if (fid < 1048576) { src = hs; dst = hs_b; local = fid; }
  else if (fid < 1310720) { src = wq; dst = wq_b; local = fid - 1048576; }
  else if (fid < 1572864) { src = wk; dst = wk_b; local = fid - 1310720; }
  else { src = wv; dst = wv_b; local = fid - 1572864; }
  float4 v = reinterpret_cast<const float4*>(src)[local];
  ushort4 o;
  o.x = f2bf(v.x); o.y = f2bf(v.y); o.z = f2bf(v.z); o.w = f2bf(v.w);
  reinterpret_cast<ushort4*>(dst)[local] = o;
}

// ---------------- kernel 2: fused QKV projection (gemm_bt, 32x32x16 MFMA) ----------------
// C[m,n] = sum_k A[m,k] * W[n,k] + bias[n].  A: [4096,1024] bf16, W: [1024,1024] bf16.
// 128x128 tile, BK=32, unpadded LDS (global_load_lds lane-contiguous constraint).
// Wave = 64x64 sub-tile = 2x2 of 32x32x16 MFMA.
#define BKK 32
__global__ __launch_bounds__(256) void qkv_gemm_kernel(
    const u16* __restrict__ A,
    const u16* __restrict__ Wq, const u16* __restrict__ Wk, const u16* __restrict__ Wv,
    const float* __restrict__ bq, const float* __restrict__ bk, const float* __restrict__ bv,
    u16* __restrict__ Qo, u16* __restrict__ Ko, u16* __restrict__ Vo) {
  __shared__ u16 sA[128 * BKK];
  __shared__ u16 sB[128 * BKK];
  const int mt = blockIdx.y, ntall = blockIdx.x;
  const int seg = ntall >> 3, nt = ntall & 7;
  const u16* Wp = (seg == 0) ? Wq : (seg == 1) ? Wk : Wv;
  const float* bp = (seg == 0) ? bq : (seg == 1) ? bk : bv;
  u16* Out = (seg == 0) ? Qo : (seg == 1) ? Ko : Vo;
  const int m0 = mt * 128, n0 = nt * 128;
  const int tid = threadIdx.x;
  const int lane = tid & 63, wave = tid >> 6;
  const int wm = (wave >> 1) * 64, wn = (wave & 1) * 64;
  const int l32 = lane & 31, khalf = lane >> 5;   // A/B operand: m=lane&31, k=khalf*8+j
  // staging coords: per wave 2 chunks of 1024B; lane covers 16B, lane-contiguous in LDS.
  const int srow0 = wave * 32 + (lane >> 2);
  const int scol = (lane & 3) * 8;
  floatx16 acc[2][2] = {};
  for (int k0 = 0; k0 < DD; k0 += BKK) {
#pragma unroll
    for (int c = 0; c < 2; ++c) {
      int r = srow0 + c * 16;
      gload16(A + (size_t)(m0 + r) * DD + k0 + scol, sA + r * BKK + scol);
      gload16(Wp + (size_t)(n0 + r) * DD + k0 + scol, sB + r * BKK + scol);
    }
    __syncthreads();  // drains vmcnt(0) -> LDS tiles complete
#pragma unroll
    for (int kk = 0; kk < 2; ++kk) {
      bf16x8 af[2], bfr[2];
#pragma unroll
      for (int i = 0; i < 2; ++i)
        af[i] = *reinterpret_cast<const bf16x8*>(sA + (wm + i * 32 + l32) * BKK + kk * 16 + khalf * 8);
#pragma unroll
      for (int j = 0; j < 2; ++j)
        bfr[j] = *reinterpret_cast<const bf16x8*>(sB + (wn + j * 32 + l32) * BKK + kk * 16 + khalf * 8);
#pragma unroll
      for (int i = 0; i < 2; ++i)
#pragma unroll
        for (int j = 0; j < 2; ++j)
          acc[i][j] = __builtin_amdgcn_mfma_f32_32x32x16_bf16(af[i], bfr[j], acc[i][j], 0, 0, 0);
    }
    __syncthreads();
  }
  // epilogue: C/D layout col=lane&31, row=(reg&3)+8*(reg>>2)+4*(lane>>5)
#pragma unroll
  for (int j = 0; j < 2; ++j) {
    int col = n0 + wn + j * 32 + l32;
    float bias = bp[col];
#pragma unroll
    for (int i = 0; i < 2; ++i) {
#pragma unroll
      for (int reg = 0; reg < 16; ++reg) {
        int row = m0 + wm + i * 32 + (reg & 3) + 8 * (reg >> 2) + 4 * khalf;
        Out[(size_t)row * DD + col] = f2bf(acc[i][j][reg] + bias);
      }
    }
  }
}

// ---------------- kernel 3: mpart[pc][bh][e][d] = sum_{s in chunk pc} mask[s]*K[s,e]*V[s,d] ----------------
// grid (8 superchunks of 256 s-rows, 32 bh); block 256, thread = 4x4 (e,d) tile. No atomics.
__global__ __launch_bounds__(256) void m_partial_kernel(
    const u16* __restrict__ Kb, const u16* __restrict__ Vb,
    const float* __restrict__ am, float* __restrict__ mpart) {
  __shared__ float sK[64 * 68];
  __shared__ float sV[64 * 68];
  const int bh = blockIdx.y;     // 0..31
  const int b = bh >> 4, h = bh & 15;
  const int tid = threadIdx.x;
  const int e0 = (tid & 15) * 4, d0 = (tid >> 4) * 4;
  float acc[4][4] = {};
  for (int cs = 0; cs < 4; ++cs) {
    const int s0 = (blockIdx.x * 4 + cs) * 64;
    if (cs) __syncthreads();  // protect LDS before restage
#pragma unroll
    for (int c = 0; c < 2; ++c) {
      int L = tid + c * 256;
      int srow = L >> 3;            // 0..63
      int col = (L & 7) * 8;        // 0..56
      size_t g = (size_t)(b * SS + s0 + srow) * DD + h * HDIM + col;
      uint4 kraw = *reinterpret_cast<const uint4*>(Kb + g);
      uint4 vraw = *reinterpret_cast<const uint4*>(Vb + g);
      float m = (am[b * SS + s0 + srow] >= 0.f) ? 1.f : 0.f;
      unsigned int kw[4] = {kraw.x, kraw.y, kraw.z, kraw.w};
      unsigned int vw[4] = {vraw.x, vraw.y, vraw.z, vraw.w};
#pragma unroll
      for (int q = 0; q < 4; ++q) {
        sK[srow * 68 + col + 2 * q]     = m * bf2f((u16)(kw[q] & 0xffffu));
        sK[srow * 68 + col + 2 * q + 1] = m * bf2f((u16)(kw[q] >> 16));
        sV[srow * 68 + col + 2 * q]     = bf2f((u16)(vw[q] & 0xffffu));
        sV[srow * 68 + col + 2 * q + 1] = bf2f((u16)(vw[q] >> 16));
      }
    }
    __syncthreads();
    for (int s = 0; s < 64; ++s) {
      float4 kk = *reinterpret_cast<const float4*>(&sK[s * 68 + e0]);
      float4 vv = *reinterpret_cast<const float4*>(&sV[s * 68 + d0]);
      float ka[4] = {kk.x, kk.y, kk.z, kk.w};
      float va[4] = {vv.x, vv.y, vv.z, vv.w};
#pragma unroll
      for (int i = 0; i < 4; ++i)
#pragma unroll
        for (int j = 0; j < 4; ++j) acc[i][j] += ka[i] * va[j];
    }
  }
  float* outp = mpart + ((size_t)(blockIdx.x * 32 + bh)) * 4096;
#pragma unroll
  for (int i = 0; i < 4; ++i) {
    float4 o = {acc[i][0], acc[i][1], acc[i][2], acc[i][3]};
    *reinterpret_cast<float4*>(&outp[(e0 + i) * 64 + d0]) = o;
  }
}

// ---------------- kernel 4: ctx[m, h*64+d] = sum_e Q[m, h*64+e] * M[bh,e,d] ----------------
// grid (64 m-chunks of 64, 16 heads); block 256, thread = 4x4 (m,d) tile, e-chunks of 4.
// M is reduced from the 8 mpart partials during LDS staging (mpart is L2-resident, 4 MB).
__global__ __launch_bounds__(256) void ctx_kernel(
    const u16* __restrict__ Qb, const float* __restrict__ mpart, float* __restrict__ Out) {
  __shared__ float sM[64 * 68];
  __shared__ float sQ[64 * 68];
  const int mchunk = blockIdx.x;  // 0..63
  const int h = blockIdx.y;       // 0..15
  const int m0 = mchunk * 64;
  const int b = m0 >> 11;         // m0 / 2048
  const int bh = b * HH + h;
  const int tid = threadIdx.x;
#pragma unroll
  for (int c = 0; c < 4; ++c) {
    int L4 = c * 256 + tid;       // float4 index 0..1023 within the 64x64 M block
    float4 s = {0.f, 0.f, 0.f, 0.f};
#pragma unroll
    for (int pc = 0; pc < 8; ++pc) {
      const float4* p4 = reinterpret_cast<const float4*>(mpart + ((size_t)(pc * 32 + bh)) * 4096);
      float4 t = p4[L4];
      s.x += t.x; s.y += t.y; s.z += t.z; s.w += t.w;
    }
    int e = L4 >> 4, d = (L4 & 15) * 4;
    *reinterpret_cast<float4*>(&sM[e * 68 + d]) = s;
  }
#pragma unroll
  for (int c = 0; c < 2; ++c) {
    int L = tid + c * 256;
    int row = L >> 3, col = (L & 7) * 8;
    uint4 q = *reinterpret_cast<const uint4*>(Qb + (size_t)(m0 + row) * DD + h * HDIM + col);
    unsigned int w[4] = {q.x, q.y, q.z, q.w};
#pragma unroll
    for (int t = 0; t < 4; ++t) {
      sQ[row * 68 + col + 2 * t]     = bf2f((u16)(w[t] & 0xffffu));
      sQ[row * 68 + col + 2 * t + 1] = bf2f((u16)(w[t] >> 16));
    }
  }
  __syncthreads();
  const int d0 = (tid & 15) * 4, ml0 = (tid >> 4) * 4;
  float acc[4][4] = {};
  for (int e4 = 0; e4 < 64; e4 += 4) {
    float4 mm[4], qq[4];
#pragma unroll
    for (int t = 0; t < 4; ++t)
      mm[t] = *reinterpret_cast<const float4*>(&sM[(e4 + t) * 68 + d0]);
#pragma unroll
    for (int i = 0; i < 4; ++i)
      qq[i] = *reinterpret_cast<const float4*>(&sQ[(ml0 + i) * 68 + e4]);
    float ma[4][4], qa[4][4];
#pragma unroll
    for (int t = 0; t < 4; ++t) {
      ma[t][0] = mm[t].x; ma[t][1] = mm[t].y; ma[t][2] = mm[t].z; ma[t][3] = mm[t].w;
      qa[t][0] = qq[t].x; qa[t][1] = qq[t].y; qa[t][2] = qq[t].z; qa[t][3] = qq[t].w;
    }
#pragma unroll
    for (int i = 0; i < 4; ++i)
#pragma unroll
      for (int t = 0; t < 4; ++t)
#pragma unroll
        for (int j = 0; j < 4; ++j)
          acc[i][j] += qa[i][t] * ma[t][j];
  }
#pragma unroll
  for (int i = 0; i < 4; ++i) {
    float4 o = {acc[i][0], acc[i][1], acc[i][2], acc[i][3]};
    *reinterpret_cast<float4*>(Out + (size_t)(m0 + ml0 + i) * DD + h * HDIM + d0) = o;
  }
}

extern "C" void kernel_launch(void* const* d_in, const int* in_sizes, int n_in,
                              void* d_out, int out_size, void* d_ws, size_t ws_size,
                              hipStream_t stream) {
  const float* hs = (const float*)d_in[0];
  const float* am = (const float*)d_in[1];
  const float* wq = (const float*)d_in[2];
  const float* bq = (const float*)d_in[3];
  const float* wk = (const float*)d_in[4];
  const float* bk = (const float*)d_in[5];
  const float* wv = (const float*)d_in[6];
  const float* bv = (const float*)d_in[7];
  float* out = (float*)d_out;
  char* ws = (char*)d_ws;

  // workspace layout (bytes), all 16B-aligned; total ~44 MB
  u16* hs_b = (u16*)(ws);                  // 8 MiB  [4096,1024] bf16
  u16* wq_b = (u16*)(ws + 8388608);        // 2 MiB
  u16* wk_b = (u16*)(ws + 10485760);       // 2 MiB
  u16* wv_b = (u16*)(ws + 12582912);       // 2 MiB
  u16* q_b  = (u16*)(ws + 14680064);       // 8 MiB
  u16* k_b  = (u16*)(ws + 23068672);       // 8 MiB
  u16* v_b  = (u16*)(ws + 31457280);       // 8 MiB
  float* mpart = (float*)(ws + 39845888);  // 4 MiB [8 pc][32 bh][64][64] f32

  cast_to_bf16<<<7168, 256, 0, stream>>>(hs, wq, wk, wv, hs_b, wq_b, wk_b, wv_b);
  qkv_gemm_kernel<<<dim3(24, 32), 256, 0, stream>>>(hs_b, wq_b, wk_b, wv_b,
                                                    bq, bk, bv, q_b, k_b, v_b);
  m_partial_kernel<<<dim3(8, 32), 256, 0, stream>>>(k_b, v_b, am, mpart);
  ctx_kernel<<<dim3(64, 16), 256, 0, stream>>>(q_b, mpart, out);
}